// Round 1
// baseline (210.944 us; speedup 1.0000x reference)
//
#include <hip/hip_runtime.h>

#define FEAT_DIM 8
#define RES 128
#define MAP_NUM 128
#define MAP_OFFSET (RES * RES)

// One thread per (batch, map) pair.
// inputs:     (32768, 128, 2)  f32
// embeddings: (128*16384, 8)   f32
// out:        (32768, 128, 10) f32  = [feats(8), xf(2)]
__global__ __launch_bounds__(256) void densemap_fwd(
    const float* __restrict__ inputs,
    const float* __restrict__ emb,
    float* __restrict__ out,
    int total)
{
    int idx = blockIdx.x * blockDim.x + threadIdx.x;
    if (idx >= total) return;

    int m = idx & (MAP_NUM - 1);

    // coalesced 8B/lane input load
    float2 in2 = *reinterpret_cast<const float2*>(inputs + (size_t)idx * 2);

    float x0 = in2.x * (float)(RES - 1);
    float x1 = in2.y * (float)(RES - 1);
    int xi0 = (int)x0;          // x >= 0, trunc == floor
    int xi1 = (int)x1;
    float xf0 = x0 - (float)xi0;
    float xf1 = x1 - (float)xi1;

    // row ids: corner (xi0,xi1) at base; (xi0,xi1+1)=base+1;
    // (xi0+1,xi1)=base+RES; (xi0+1,xi1+1)=base+RES+1
    size_t base = (size_t)m * MAP_OFFSET + (size_t)xi0 * RES + xi1;

    const float4* e4 = reinterpret_cast<const float4*>(emb);
    // each 8-float row = two float4 at indices 2r, 2r+1 (32B aligned)
    float4 r00a = e4[2 * base];
    float4 r00b = e4[2 * base + 1];
    float4 r01a = e4[2 * (base + 1)];
    float4 r01b = e4[2 * (base + 1) + 1];
    float4 r10a = e4[2 * (base + RES)];
    float4 r10b = e4[2 * (base + RES) + 1];
    float4 r11a = e4[2 * (base + RES + 1)];
    float4 r11b = e4[2 * (base + RES + 1) + 1];

    float w00 = (1.0f - xf0) * (1.0f - xf1);  // (xi0,   xi1)
    float w01 = (1.0f - xf0) * xf1;           // (xi0,   xi1+1)
    float w10 = xf0 * (1.0f - xf1);           // (xi0+1, xi1)
    float w11 = xf0 * xf1;                    // (xi0+1, xi1+1)

    float f0 = r00a.x * w00 + r01a.x * w01 + r10a.x * w10 + r11a.x * w11;
    float f1 = r00a.y * w00 + r01a.y * w01 + r10a.y * w10 + r11a.y * w11;
    float f2 = r00a.z * w00 + r01a.z * w01 + r10a.z * w10 + r11a.z * w11;
    float f3 = r00a.w * w00 + r01a.w * w01 + r10a.w * w10 + r11a.w * w11;
    float f4 = r00b.x * w00 + r01b.x * w01 + r10b.x * w10 + r11b.x * w11;
    float f5 = r00b.y * w00 + r01b.y * w01 + r10b.y * w10 + r11b.y * w11;
    float f6 = r00b.z * w00 + r01b.z * w01 + r10b.z * w10 + r11b.z * w11;
    float f7 = r00b.w * w00 + r01b.w * w01 + r10b.w * w10 + r11b.w * w11;

    // 40B per thread, 8B-aligned: 5 x float2 stores
    float* o = out + (size_t)idx * 10;
    float2* o2 = reinterpret_cast<float2*>(o);
    o2[0] = make_float2(f0, f1);
    o2[1] = make_float2(f2, f3);
    o2[2] = make_float2(f4, f5);
    o2[3] = make_float2(f6, f7);
    o2[4] = make_float2(xf0, xf1);
}

extern "C" void kernel_launch(void* const* d_in, const int* in_sizes, int n_in,
                              void* d_out, int out_size, void* d_ws, size_t ws_size,
                              hipStream_t stream) {
    const float* inputs = (const float*)d_in[0];      // 32768*128*2
    const float* emb    = (const float*)d_in[1];      // 128*16384*8
    float* out          = (float*)d_out;              // 32768*128*10

    int total = in_sizes[0] / 2;                      // 32768*128
    int block = 256;
    int grid = (total + block - 1) / block;
    densemap_fwd<<<grid, block, 0, stream>>>(inputs, emb, out, total);
}

// Round 3
// 150.734 us; speedup vs baseline: 1.3995x; 1.3995x over previous
//
#include <hip/hip_runtime.h>

#define FEAT_DIM 8
#define RES 128
#define MAP_NUM 128
#define MAP_OFFSET (RES * RES)

typedef float v2f __attribute__((ext_vector_type(2)));
typedef float v4f __attribute__((ext_vector_type(4)));

// Work decomposition for L2 locality:
//   block = 256 threads = 32 batch x 8 maps (lane: ml = tid&7 fastest)
//   -> each block gathers from an 8-map subtable = 8*16384*32B = 4MB (one XCD L2)
//   XCD swizzle: block g -> XCD g%8 (dispatch round-robin); XCD x owns map
//   groups 2x, 2x+1 (maps 16x..16x+15), walking all 1024 b-chunks of a group
//   before the next -> one ~4MB subtable hot per XCD L2 at a time.
// I/O stays fully coalesced: input segments 64B aligned, output segments 320B
// aligned (m0 multiple of 8). Streaming I/O uses nontemporal hints to avoid
// evicting the gather working set from L2.
__global__ __launch_bounds__(256) void densemap_fwd(
    const float* __restrict__ inputs,
    const float* __restrict__ emb,
    float* __restrict__ out)
{
    int g = blockIdx.x;
    int x  = g & 7;          // XCD id (by dispatch round-robin)
    int t  = g >> 3;         // 0..2047 per XCD
    int gl = t >> 10;        // which of this XCD's 2 map-groups
    int c  = t & 1023;       // b-chunk within group
    int m0 = ((x << 1) + gl) << 3;   // first map of group (multiple of 8)
    int b0 = c << 5;                 // 32 batch items per block

    int ml = threadIdx.x & 7;
    int bl = threadIdx.x >> 3;
    int m = m0 + ml;
    int b = b0 + bl;
    int idx = b * MAP_NUM + m;       // < 2^22, fits int

    // coalesced (64B full-line) streaming input load
    const v2f* inp2 = reinterpret_cast<const v2f*>(inputs);
    v2f in2 = __builtin_nontemporal_load(inp2 + idx);

    float x0 = in2.x * (float)(RES - 1);
    float x1 = in2.y * (float)(RES - 1);
    int xi0 = (int)x0;               // x >= 0, trunc == floor
    int xi1 = (int)x1;
    float xf0 = x0 - (float)xi0;
    float xf1 = x1 - (float)xi1;

    // corner rows: base, base+1, base+RES, base+RES+1
    size_t base = (size_t)m * MAP_OFFSET + (size_t)xi0 * RES + xi1;

    const v4f* e4 = reinterpret_cast<const v4f*>(emb);
    v4f r00a = e4[2 * base];
    v4f r00b = e4[2 * base + 1];
    v4f r01a = e4[2 * (base + 1)];
    v4f r01b = e4[2 * (base + 1) + 1];
    v4f r10a = e4[2 * (base + RES)];
    v4f r10b = e4[2 * (base + RES) + 1];
    v4f r11a = e4[2 * (base + RES + 1)];
    v4f r11b = e4[2 * (base + RES + 1) + 1];

    float w00 = (1.0f - xf0) * (1.0f - xf1);
    float w01 = (1.0f - xf0) * xf1;
    float w10 = xf0 * (1.0f - xf1);
    float w11 = xf0 * xf1;

    v4f fa = r00a * w00 + r01a * w01 + r10a * w10 + r11a * w11;
    v4f fb = r00b * w00 + r01b * w01 + r10b * w10 + r11b * w11;

    // 40B per thread, 8B-aligned: 5 x v2f nontemporal stores
    v2f* o2 = reinterpret_cast<v2f*>(out + (size_t)idx * 10);
    v2f s0 = {fa.x, fa.y};
    v2f s1 = {fa.z, fa.w};
    v2f s2 = {fb.x, fb.y};
    v2f s3 = {fb.z, fb.w};
    v2f s4 = {xf0, xf1};
    __builtin_nontemporal_store(s0, o2 + 0);
    __builtin_nontemporal_store(s1, o2 + 1);
    __builtin_nontemporal_store(s2, o2 + 2);
    __builtin_nontemporal_store(s3, o2 + 3);
    __builtin_nontemporal_store(s4, o2 + 4);
}

extern "C" void kernel_launch(void* const* d_in, const int* in_sizes, int n_in,
                              void* d_out, int out_size, void* d_ws, size_t ws_size,
                              hipStream_t stream) {
    const float* inputs = (const float*)d_in[0];      // 32768*128*2
    const float* emb    = (const float*)d_in[1];      // 128*16384*8
    float* out          = (float*)d_out;              // 32768*128*10

    // 16 map-groups (8 maps each) x 1024 b-chunks (32 b each) = 16384 blocks
    int grid = 16384;
    densemap_fwd<<<grid, 256, 0, stream>>>(inputs, emb, out);
}